// Round 3
// baseline (432.906 us; speedup 1.0000x reference)
//
#include <hip/hip_runtime.h>
#include <hip/hip_bf16.h>
#include <math.h>

// Problem constants (match reference)
#define HEADS 8
#define HC 256            // HEADS*CHAN = D
#define NEG_SLOPE 0.2f    // leaky(t) = max(t, 0.2t)

typedef __attribute__((ext_vector_type(8))) short short8;
typedef __attribute__((ext_vector_type(16))) float floatx16;
typedef __attribute__((ext_vector_type(2))) float v2f;

__device__ inline ushort bf16_rne(float f) {
    unsigned u = __float_as_uint(f);
    return (ushort)((u + 0x7FFFu + ((u >> 16) & 1u)) >> 16);
}

// unpack 2 bf16 (packed in a dword) to 2 f32: lo = bits<<16, hi = bits&hi-mask
__device__ __forceinline__ v2f unpk2(unsigned u) {
    v2f r;
    r.x = __uint_as_float(u << 16);
    r.y = __uint_as_float(u & 0xffff0000u);
    return r;
}

// butterfly add over 4-lane quad via DPP (no LDS pipe): xor1 then xor2
__device__ __forceinline__ float quad_add(float x) {
    x += __int_as_float(__builtin_amdgcn_mov_dpp(
        __float_as_int(x), 0xB1, 0xF, 0xF, true));   // quad_perm(1,0,3,2)
    x += __int_as_float(__builtin_amdgcn_mov_dpp(
        __float_as_int(x), 0x4E, 0xF, 0xF, true));   // quad_perm(2,3,0,1)
    return x;
}

// ---------------------------------------------------------------------------
// fp32 -> bf16 convert of x with XOR-swizzled layout: 16B block j of row r
// stored at block position j ^ (r&7). GEMM then DMA-stages rows verbatim and
// fragment ds_read_b128s land on all 8 bank-groups (b128 floor).
__global__ __launch_bounds__(256) void cvt_bf16_sw(
        const float* __restrict__ x, ushort* __restrict__ xb, long long nblk) {
    long long id = (long long)blockIdx.x * blockDim.x + threadIdx.x;
    if (id >= nblk) return;
    long long r = id >> 5;
    int j = (int)(id & 31);
    const float4* p = (const float4*)(x + id * 8);
    float4 a = p[0], b = p[1];
    short8 pk;
    pk[0] = (short)bf16_rne(a.x); pk[1] = (short)bf16_rne(a.y);
    pk[2] = (short)bf16_rne(a.z); pk[3] = (short)bf16_rne(a.w);
    pk[4] = (short)bf16_rne(b.x); pk[5] = (short)bf16_rne(b.y);
    pk[6] = (short)bf16_rne(b.z); pk[7] = (short)bf16_rne(b.w);
    int jx = j ^ ((int)r & 7);
    *(short8*)(xb + r * 256 + jx * 8) = pk;
}

// ---------------------------------------------------------------------------
// Pre-transpose weights into wt[n][k] bf16, same XOR swizzle (row = n).
__global__ __launch_bounds__(256) void build_wt(
        const float* __restrict__ Wl, const float* __restrict__ Wr,
        ushort* __restrict__ wt) {
    int n = blockIdx.x;            // 0..511
    int k = threadIdx.x;           // 0..255
    const float* W = (n < 256) ? Wl : Wr;
    int col = n & 255;
    int jx = (k >> 3) ^ (n & 7);
    wt[n * HC + jx * 8 + (k & 7)] = bf16_rne(W[k * HC + col]);
}

// ---------------------------------------------------------------------------
// MFMA dual-GEMM: C[N,512] = A[N,256](bf16,swz) x wt(bf16,swz), bf16 out.
// 64x64 C-tile, K=256 fully staged via global_load_lds width-16 DMA.
// Supergrouped block mapping: within a 128-block group, the 8 nt-copies of
// each mt share identical low-3 bits of blockIdx (-> same XCD under bid%8
// round-robin) and are temporally adjacent -> A-tile staged past-L2 once,
// then 7x L2 hits. 4 waves, each a 32x32 quadrant via mfma_32x32x16_bf16.
__global__ __launch_bounds__(256) void gemm_mfma(
        const ushort* __restrict__ A, const ushort* __restrict__ wt,
        ushort* __restrict__ xl, ushort* __restrict__ xr, int N) {
    __shared__ ushort lA[64 * 256];
    __shared__ ushort lB[64 * 256];
    int local = blockIdx.x & 127;
    int grp   = blockIdx.x >> 7;
    int mt = grp * 16 + (local & 15);   // same XCD for all nt of this mt
    int nt = local >> 4;
    int m0 = mt * 64, n0 = nt * 64;
    int t = threadIdx.x;
    int lane = t & 63, wv = t >> 6;

    // ---- DMA staging: each wave copies 8x 1KB chunks of A and of B ----
    {
        const ushort* gA = A + (long long)m0 * HC;   // rows contiguous (swz)
        const ushort* gB = wt + (long long)n0 * HC;
        #pragma unroll
        for (int i = 0; i < 8; ++i) {
            int off = (wv * 8 + i) * 512;            // ushorts (1 KB chunks)
            __builtin_amdgcn_global_load_lds(
                (const __attribute__((address_space(1))) unsigned int*)(gA + off + lane * 8),
                (__attribute__((address_space(3))) unsigned int*)(lA + off), 16, 0, 0);
            __builtin_amdgcn_global_load_lds(
                (const __attribute__((address_space(1))) unsigned int*)(gB + off + lane * 8),
                (__attribute__((address_space(3))) unsigned int*)(lB + off), 16, 0, 0);
        }
    }
    __syncthreads();

    // ---- k-loop: wave quadrant rows (wv&1)*32, cols (wv>>1)*32 ----
    int rA = (wv & 1) * 32 + (lane & 31);
    int rB = (wv >> 1) * 32 + (lane & 31);
    int kh = lane >> 5;                // k-half of the fragment
    int sA = rA & 7, sB = rB & 7;
    floatx16 acc;
    #pragma unroll
    for (int i = 0; i < 16; ++i) acc[i] = 0.f;
    #pragma unroll
    for (int step = 0; step < 16; ++step) {
        int j = step * 2 + kh;
        short8 a = *(const short8*)&lA[rA * 256 + ((j ^ sA) * 8)];
        short8 b = *(const short8*)&lB[rB * 256 + ((j ^ sB) * 8)];
        acc = __builtin_amdgcn_mfma_f32_32x32x16_bf16(a, b, acc, 0, 0, 0);
    }

    // ---- epilogue: C/D layout col=lane&31, row=(reg&3)+8*(reg>>2)+4*kh ----
    ushort* obase = (nt < 4) ? xl : xr;               // xl/xr are PLAIN layout
    int colb = (n0 & 255) + (wv >> 1) * 32 + (lane & 31);
    int rbase = m0 + (wv & 1) * 32 + 4 * kh;
    #pragma unroll
    for (int g = 0; g < 4; ++g) {
        #pragma unroll
        for (int q = 0; q < 4; ++q) {
            int row = rbase + q + 8 * g;
            if (row < N)
                obase[(long long)row * HC + colb] = bf16_rne(acc[g * 4 + q]);
        }
    }
}

// ---------------------------------------------------------------------------
// Histogram of dst (self-loops appended implicitly: edge w>=E is node w-E)
__global__ void hist_dst(const int* __restrict__ eidx, int E, int N,
                         int* __restrict__ counts) {
    int w = blockIdx.x * blockDim.x + threadIdx.x;
    int Etot = E + N;
    if (w >= Etot) return;
    int d = (w < E) ? eidx[E + w] : (w - E);
    atomicAdd(&counts[d], 1);
}

// ---------------------------------------------------------------------------
// 3-kernel exclusive scan: per-block scan -> block-sum scan -> add offsets
__global__ __launch_bounds__(1024) void scan_local(
        const int* __restrict__ counts, int* __restrict__ rowptr,
        int* __restrict__ bsum, int N) {
    __shared__ int wsums[16];
    int t = threadIdx.x, lane = t & 63, wv = t >> 6;
    int i = blockIdx.x * 1024 + t;
    int v = (i < N) ? counts[i] : 0;
    int orig = v;
    #pragma unroll
    for (int off = 1; off < 64; off <<= 1) {
        int n = __shfl_up(v, off, 64);
        if (lane >= off) v += n;
    }
    if (lane == 63) wsums[wv] = v;
    __syncthreads();
    int woff = 0, total = 0;
    #pragma unroll
    for (int w_ = 0; w_ < 16; ++w_) {
        int s = wsums[w_];
        if (w_ < wv) woff += s;
        total += s;
    }
    if (i < N) rowptr[i] = v + woff - orig;
    if (t == 0) bsum[blockIdx.x] = total;
}

__global__ void scan_bsums(const int* __restrict__ bsum, int* __restrict__ bsum2,
                           int* __restrict__ rowptr, int nb, int N) {
    int lane = threadIdx.x;   // 64 threads, nb <= 64
    int v = (lane < nb) ? bsum[lane] : 0;
    int orig = v;
    #pragma unroll
    for (int off = 1; off < 64; off <<= 1) {
        int n = __shfl_up(v, off, 64);
        if (lane >= off) v += n;
    }
    if (lane < nb) bsum2[lane] = v - orig;
    if (lane == 63) rowptr[N] = v;
}

__global__ __launch_bounds__(1024) void scan_add(
        int* __restrict__ rowptr, const int* __restrict__ bsum2, int N) {
    int i = blockIdx.x * 1024 + threadIdx.x;
    if (i < N) rowptr[i] += bsum2[blockIdx.x];
}

// ---------------------------------------------------------------------------
// Scatter: store PRE-SCALED byte offsets (s * 512 = s<<9) so gat_node's
// gather address is a single v_or with the lane's channel-byte offset.
__global__ void scatter_edges(const int* __restrict__ eidx, int E, int N,
                              const int* __restrict__ rowptr,
                              int* __restrict__ fill, int* __restrict__ srcS) {
    int w = blockIdx.x * blockDim.x + threadIdx.x;
    int Etot = E + N;
    if (w >= Etot) return;
    int s, d;
    if (w < E) { s = eidx[w]; d = eidx[E + w]; }
    else       { s = w - E;   d = w - E; }
    int pos = rowptr[d] + atomicAdd(&fill[d], 1);
    srcS[pos] = s << 9;          // byte offset of row s (HC * 2B = 512)
}

// ---------------------------------------------------------------------------
// Fused GATv2 per-node: one wave per dst node. Two edges per wave per pair
// (half-waves h=0/1), 8 channels per lane (one dwordx4 gather per lane).
// R7 structure (MLP-focused; R6's depth-1 rotation was a regression):
//  * main loop = 4 pairs (8 edges): 4 INDEPENDENT gathers issued back-to-back
//    before any compute (MLP=4/wave), masks only in the tail.
//  * index prefetch depth-1: iteration i loads iteration i+1's 4 indices,
//    so the next gathers issue with no index-load latency in front
//    (srcS holds byte offsets; padded by 8 zeroed ints -> unconditional).
//  * DPP quad butterfly for the score reduce (no LDS pipe).
//  * packed f32 math (v_pk_add/mul/fma/max); leaky as max(t, 0.2t) (exact);
//    accumulate ex*t, correct with -xr at the end (t = v + xr).
// LAYER1: ELU + bf16 SWIZZLED store (feeds layer-2 GEMM DMA); else fp32.
template <int LAYER1>
__global__ __launch_bounds__(256) void gat_node(
        const ushort* __restrict__ xl, const ushort* __restrict__ xr,
        const float* __restrict__ att, const float* __restrict__ bias,
        const int* __restrict__ rowptr, const unsigned* __restrict__ srcB,
        void* __restrict__ outp, int N) {
    int node = blockIdx.x * 4 + (threadIdx.x >> 6);
    int lane = threadIdx.x & 63;
    if (node >= N) return;
    int h = lane >> 5;                       // which edge of the pair
    int q = lane & 31;                       // 16B-block index within row
    unsigned cb = (unsigned)q * 16u;         // byte offset within row
    int beg = rowptr[node], end = rowptr[node + 1];

    long long nbase = (long long)node * HC;
    uint4 xu = *(const uint4*)(xr + nbase + q * 8);
    v2f X0 = unpk2(xu.x), X1 = unpk2(xu.y), X2 = unpk2(xu.z), X3 = unpk2(xu.w);
    v2f A0 = *(const v2f*)(att + q * 8);
    v2f A1 = *(const v2f*)(att + q * 8 + 2);
    v2f A2 = *(const v2f*)(att + q * 8 + 4);
    v2f A3 = *(const v2f*)(att + q * 8 + 6);

    float ssA = 0.f, ssB = 0.f;
    v2f C0 = {0.f, 0.f}, C1 = {0.f, 0.f}, C2 = {0.f, 0.f}, C3 = {0.f, 0.f};

    const char* xb = (const char*)xl;

// Process one edge-pair from gathered data DV. MASKED only in the tail.
#define PAIRBODY(DV, SS, MASKED, VALID)                                        \
    {                                                                          \
        v2f t0 = unpk2(DV.x) + X0;                                             \
        v2f t1 = unpk2(DV.y) + X1;                                             \
        v2f t2 = unpk2(DV.z) + X2;                                             \
        v2f t3 = unpk2(DV.w) + X3;                                             \
        v2f l0 = __builtin_elementwise_max(t0, t0 * NEG_SLOPE);                \
        v2f l1 = __builtin_elementwise_max(t1, t1 * NEG_SLOPE);                \
        v2f l2 = __builtin_elementwise_max(t2, t2 * NEG_SLOPE);                \
        v2f l3 = __builtin_elementwise_max(t3, t3 * NEG_SLOPE);                \
        v2f d = A0 * l0;                                                       \
        d = __builtin_elementwise_fma(A1, l1, d);                              \
        d = __builtin_elementwise_fma(A2, l2, d);                              \
        d = __builtin_elementwise_fma(A3, l3, d);                              \
        float sc = quad_add(d.x + d.y);                                        \
        float ex = __expf(sc);                                                 \
        if (MASKED) ex = (VALID) ? ex : 0.f;                                   \
        SS += ex;                                                              \
        v2f e2 = {ex, ex};                                                     \
        C0 = __builtin_elementwise_fma(e2, t0, C0);                            \
        C1 = __builtin_elementwise_fma(e2, t1, C1);                            \
        C2 = __builtin_elementwise_fma(e2, t2, C2);                            \
        C3 = __builtin_elementwise_fma(e2, t3, C3);                            \
    }

    int p = beg;
    if (p + 8 <= end) {
        unsigned i0 = srcB[p + h],     i1 = srcB[p + 2 + h];
        unsigned i2 = srcB[p + 4 + h], i3 = srcB[p + 6 + h];
        for (;;) {
            // 4 independent gathers, issued before any compute
            uint4 d0 = *(const uint4*)(xb + (i0 | cb));
            uint4 d1 = *(const uint4*)(xb + (i1 | cb));
            uint4 d2 = *(const uint4*)(xb + (i2 | cb));
            uint4 d3 = *(const uint4*)(xb + (i3 | cb));
            // prefetch next iteration's indices (pad makes this always safe)
            int pn = p + 8;
            i0 = srcB[pn + h];     i1 = srcB[pn + 2 + h];
            i2 = srcB[pn + 4 + h]; i3 = srcB[pn + 6 + h];
            PAIRBODY(d0, ssA, 0, 1)
            PAIRBODY(d1, ssB, 0, 1)
            PAIRBODY(d2, ssA, 0, 1)
            PAIRBODY(d3, ssB, 0, 1)
            p = pn;
            if (p + 8 > end) break;
        }
    }
    // tail: <8 edges left, 2-edge steps, masked (pad keeps reads safe)
    for (; p < end; p += 2) {
        unsigned o = srcB[p + h];
        uint4 dv = *(const uint4*)(xb + (o | cb));
        PAIRBODY(dv, ssA, 1, (p + h < end))
    }
#undef PAIRBODY

    // merge the two half-wave partial sums (once per node)
    float ss = ssA + ssB;
    ss += __shfl_xor(ss, 32, 64);
    float a0 = C0.x; a0 += __shfl_xor(a0, 32, 64);
    float a1 = C0.y; a1 += __shfl_xor(a1, 32, 64);
    float a2 = C1.x; a2 += __shfl_xor(a2, 32, 64);
    float a3 = C1.y; a3 += __shfl_xor(a3, 32, 64);
    float a4 = C2.x; a4 += __shfl_xor(a4, 32, 64);
    float a5 = C2.y; a5 += __shfl_xor(a5, 32, 64);
    float a6 = C3.x; a6 += __shfl_xor(a6, 32, 64);
    float a7 = C3.y; a7 += __shfl_xor(a7, 32, 64);

    float inv = 1.f / ss;
    float4 bv0 = *(const float4*)(bias + q * 8);
    float4 bv1 = *(const float4*)(bias + q * 8 + 4);
    // out = (sum ex*t)/ss - xr + bias   (since t = v + xr)
    float o0 = fmaf(a0, inv, bv0.x - X0.x);
    float o1 = fmaf(a1, inv, bv0.y - X0.y);
    float o2 = fmaf(a2, inv, bv0.z - X1.x);
    float o3 = fmaf(a3, inv, bv0.w - X1.y);
    float o4 = fmaf(a4, inv, bv1.x - X2.x);
    float o5 = fmaf(a5, inv, bv1.y - X2.y);
    float o6 = fmaf(a6, inv, bv1.z - X3.x);
    float o7 = fmaf(a7, inv, bv1.w - X3.y);

    if (LAYER1) {
        // each half stores its 4 channels of the 16B block q
        float s0 = h ? o4 : o0;
        float s1 = h ? o5 : o1;
        float s2 = h ? o6 : o2;
        float s3 = h ? o7 : o3;
        s0 = s0 > 0.f ? s0 : expm1f(s0);
        s1 = s1 > 0.f ? s1 : expm1f(s1);
        s2 = s2 > 0.f ? s2 : expm1f(s2);
        s3 = s3 > 0.f ? s3 : expm1f(s3);
        ushort4 pk;
        pk.x = bf16_rne(s0); pk.y = bf16_rne(s1);
        pk.z = bf16_rne(s2); pk.w = bf16_rne(s3);
        int jx = q ^ (node & 7);             // swizzled 16B-block position
        *(ushort4*)((ushort*)outp + nbase + jx * 8 + h * 4) = pk;
    } else {
        float4 ov = h ? make_float4(o4, o5, o6, o7)
                      : make_float4(o0, o1, o2, o3);
        *(float4*)((float*)outp + nbase + q * 8 + h * 4) = ov;
    }
}

// ---------------------------------------------------------------------------
extern "C" void kernel_launch(void* const* d_in, const int* in_sizes, int n_in,
                              void* d_out, int out_size, void* d_ws, size_t ws_size,
                              hipStream_t stream) {
    const float* x    = (const float*)d_in[0];
    const int*   eidx = (const int*)d_in[1];
    const float* Wl1  = (const float*)d_in[2];
    const float* Wr1  = (const float*)d_in[3];
    const float* att1 = (const float*)d_in[4];
    const float* b1   = (const float*)d_in[5];
    const float* Wl2  = (const float*)d_in[6];
    const float* Wr2  = (const float*)d_in[7];
    const float* att2 = (const float*)d_in[8];
    const float* b2   = (const float*)d_in[9];
    float* out = (float*)d_out;

    const int N = in_sizes[0] / HC;       // 50000
    const int E = in_sizes[1] / 2;        // 800000
    const int Etot = E + N;
    const long long NHC = (long long)N * HC;

    // workspace layout (16B-aligned bf16 region first)
    ushort* xl   = (ushort*)d_ws;         // N*HC bf16 (plain)
    ushort* xr   = xl + NHC;              // N*HC     (plain)
    ushort* hbuf = xr + NHC;              // N*HC     (swizzled)
    ushort* xb   = hbuf + NHC;            // N*HC     (swizzled)
    ushort* wt1  = xb + NHC;              // 512*HC   (swizzled)
    ushort* wt2  = wt1 + 512 * HC;        // 512*HC   (swizzled)
    int* rowptr  = (int*)(wt2 + 512 * HC);// N+1
    int* counts  = rowptr + (N + 1);      // N
    int* fill    = counts + N;            // N (contiguous with counts)
    int* bsum    = fill + N;              // 64
    int* bsum2   = bsum + 64;             // 64
    int* srcS    = bsum2 + 64;            // Etot + 8 (padded for prefetch)

    const int TB = 256;
    dim3 blk(TB);
    int gEdgesT = (Etot + TB - 1) / TB;
    int mtTiles = (N + 63) / 64;                  // 782
    int gGemm   = ((mtTiles + 15) / 16) * 128;    // supergrouped (16 mt x 8 nt)
    int gNode   = (N + 3) / 4;
    int nb      = (N + 1023) / 1024;      // 49 <= 64
    long long nblk = NHC / 8;
    int gCvt    = (int)((nblk + TB - 1) / TB);

    // ---- one-time conversions + CSR build ----
    cvt_bf16_sw<<<gCvt, blk, 0, stream>>>(x, xb, nblk);
    build_wt<<<512, blk, 0, stream>>>(Wl1, Wr1, wt1);
    build_wt<<<512, blk, 0, stream>>>(Wl2, Wr2, wt2);
    hipMemsetAsync(counts, 0, (size_t)2 * N * sizeof(int), stream);
    hipMemsetAsync(srcS + Etot, 0, 8 * sizeof(int), stream);  // prefetch pad
    hist_dst<<<gEdgesT, blk, 0, stream>>>(eidx, E, N, counts);
    scan_local<<<nb, 1024, 0, stream>>>(counts, rowptr, bsum, N);
    scan_bsums<<<1, 64, 0, stream>>>(bsum, bsum2, rowptr, nb, N);
    scan_add<<<nb, 1024, 0, stream>>>(rowptr, bsum2, N);
    scatter_edges<<<gEdgesT, blk, 0, stream>>>(eidx, E, N, rowptr, fill, srcS);

    // ================= layer 1 =================
    gemm_mfma<<<gGemm, blk, 0, stream>>>(xb, wt1, xl, xr, N);
    gat_node<1><<<gNode, blk, 0, stream>>>(xl, xr, att1, b1, rowptr,
                                           (const unsigned*)srcS, hbuf, N);

    // ================= layer 2 =================
    gemm_mfma<<<gGemm, blk, 0, stream>>>(hbuf, wt2, xl, xr, N);
    gat_node<0><<<gNode, blk, 0, stream>>>(xl, xr, att2, b2, rowptr,
                                           (const unsigned*)srcS, out, N);
}

// Round 4
// 430.987 us; speedup vs baseline: 1.0045x; 1.0045x over previous
//
#include <hip/hip_runtime.h>
#include <hip/hip_bf16.h>
#include <math.h>

// Problem constants (match reference)
#define HEADS 8
#define HC 256            // HEADS*CHAN = D
#define NEG_SLOPE 0.2f    // leaky(t) = 0.6*t + 0.4*|t|

typedef __attribute__((ext_vector_type(8))) short short8;
typedef __attribute__((ext_vector_type(16))) float floatx16;

__device__ inline ushort bf16_rne(float f) {
    unsigned u = __float_as_uint(f);
    return (ushort)((u + 0x7FFFu + ((u >> 16) & 1u)) >> 16);
}

// ---------------------------------------------------------------------------
// fp32 -> bf16 convert of x with XOR-swizzled layout: 16B block j of row r
// stored at block position j ^ (r&7). GEMM then DMA-stages rows verbatim and
// fragment ds_read_b128s land on all 8 bank-groups (b128 floor).
__global__ __launch_bounds__(256) void cvt_bf16_sw(
        const float* __restrict__ x, ushort* __restrict__ xb, long long nblk) {
    long long id = (long long)blockIdx.x * blockDim.x + threadIdx.x;
    if (id >= nblk) return;
    long long r = id >> 5;
    int j = (int)(id & 31);
    const float4* p = (const float4*)(x + id * 8);
    float4 a = p[0], b = p[1];
    short8 pk;
    pk[0] = (short)bf16_rne(a.x); pk[1] = (short)bf16_rne(a.y);
    pk[2] = (short)bf16_rne(a.z); pk[3] = (short)bf16_rne(a.w);
    pk[4] = (short)bf16_rne(b.x); pk[5] = (short)bf16_rne(b.y);
    pk[6] = (short)bf16_rne(b.z); pk[7] = (short)bf16_rne(b.w);
    int jx = j ^ ((int)r & 7);
    *(short8*)(xb + r * 256 + jx * 8) = pk;
}

// ---------------------------------------------------------------------------
// Pre-transpose weights into wt[n][k] bf16, same XOR swizzle (row = n).
__global__ __launch_bounds__(256) void build_wt(
        const float* __restrict__ Wl, const float* __restrict__ Wr,
        ushort* __restrict__ wt) {
    int n = blockIdx.x;            // 0..511
    int k = threadIdx.x;           // 0..255
    const float* W = (n < 256) ? Wl : Wr;
    int col = n & 255;
    int jx = (k >> 3) ^ (n & 7);
    wt[n * HC + jx * 8 + (k & 7)] = bf16_rne(W[k * HC + col]);
}

// ---------------------------------------------------------------------------
// MFMA dual-GEMM: C[N,512] = A[N,256](bf16,swz) x wt(bf16,swz), bf16 out.
// 64x64 C-tile, K=256 fully staged via global_load_lds width-16 DMA.
// Supergrouped block mapping: within a 128-block group, the 8 nt-copies of
// each mt share identical low-3 bits of blockIdx (-> same XCD under bid%8
// round-robin) and are temporally adjacent -> A-tile staged past-L2 once,
// then 7x L2 hits. 4 waves, each a 32x32 quadrant via mfma_32x32x16_bf16.
__global__ __launch_bounds__(256) void gemm_mfma(
        const ushort* __restrict__ A, const ushort* __restrict__ wt,
        ushort* __restrict__ xl, ushort* __restrict__ xr, int N) {
    __shared__ ushort lA[64 * 256];
    __shared__ ushort lB[64 * 256];
    int local = blockIdx.x & 127;
    int grp   = blockIdx.x >> 7;
    int mt = grp * 16 + (local & 15);   // same XCD for all nt of this mt
    int nt = local >> 4;
    int m0 = mt * 64, n0 = nt * 64;
    int t = threadIdx.x;
    int lane = t & 63, wv = t >> 6;

    // ---- DMA staging: each wave copies 8x 1KB chunks of A and of B ----
    {
        const ushort* gA = A + (long long)m0 * HC;   // rows contiguous (swz)
        const ushort* gB = wt + (long long)n0 * HC;
        #pragma unroll
        for (int i = 0; i < 8; ++i) {
            int off = (wv * 8 + i) * 512;            // ushorts (1 KB chunks)
            __builtin_amdgcn_global_load_lds(
                (const __attribute__((address_space(1))) unsigned int*)(gA + off + lane * 8),
                (__attribute__((address_space(3))) unsigned int*)(lA + off), 16, 0, 0);
            __builtin_amdgcn_global_load_lds(
                (const __attribute__((address_space(1))) unsigned int*)(gB + off + lane * 8),
                (__attribute__((address_space(3))) unsigned int*)(lB + off), 16, 0, 0);
        }
    }
    __syncthreads();

    // ---- k-loop: wave quadrant rows (wv&1)*32, cols (wv>>1)*32 ----
    int rA = (wv & 1) * 32 + (lane & 31);
    int rB = (wv >> 1) * 32 + (lane & 31);
    int kh = lane >> 5;                // k-half of the fragment
    int sA = rA & 7, sB = rB & 7;
    floatx16 acc;
    #pragma unroll
    for (int i = 0; i < 16; ++i) acc[i] = 0.f;
    #pragma unroll
    for (int step = 0; step < 16; ++step) {
        int j = step * 2 + kh;
        short8 a = *(const short8*)&lA[rA * 256 + ((j ^ sA) * 8)];
        short8 b = *(const short8*)&lB[rB * 256 + ((j ^ sB) * 8)];
        acc = __builtin_amdgcn_mfma_f32_32x32x16_bf16(a, b, acc, 0, 0, 0);
    }

    // ---- epilogue: C/D layout col=lane&31, row=(reg&3)+8*(reg>>2)+4*kh ----
    ushort* obase = (nt < 4) ? xl : xr;               // xl/xr are PLAIN layout
    int colb = (n0 & 255) + (wv >> 1) * 32 + (lane & 31);
    int rbase = m0 + (wv & 1) * 32 + 4 * kh;
    #pragma unroll
    for (int g = 0; g < 4; ++g) {
        #pragma unroll
        for (int q = 0; q < 4; ++q) {
            int row = rbase + q + 8 * g;
            if (row < N)
                obase[(long long)row * HC + colb] = bf16_rne(acc[g * 4 + q]);
        }
    }
}

// ---------------------------------------------------------------------------
// Histogram of dst (self-loops appended implicitly: edge w>=E is node w-E)
__global__ void hist_dst(const int* __restrict__ eidx, int E, int N,
                         int* __restrict__ counts) {
    int w = blockIdx.x * blockDim.x + threadIdx.x;
    int Etot = E + N;
    if (w >= Etot) return;
    int d = (w < E) ? eidx[E + w] : (w - E);
    atomicAdd(&counts[d], 1);
}

// ---------------------------------------------------------------------------
// 3-kernel exclusive scan: per-block scan -> block-sum scan -> add offsets
__global__ __launch_bounds__(1024) void scan_local(
        const int* __restrict__ counts, int* __restrict__ rowptr,
        int* __restrict__ bsum, int N) {
    __shared__ int wsums[16];
    int t = threadIdx.x, lane = t & 63, wv = t >> 6;
    int i = blockIdx.x * 1024 + t;
    int v = (i < N) ? counts[i] : 0;
    int orig = v;
    #pragma unroll
    for (int off = 1; off < 64; off <<= 1) {
        int n = __shfl_up(v, off, 64);
        if (lane >= off) v += n;
    }
    if (lane == 63) wsums[wv] = v;
    __syncthreads();
    int woff = 0, total = 0;
    #pragma unroll
    for (int w_ = 0; w_ < 16; ++w_) {
        int s = wsums[w_];
        if (w_ < wv) woff += s;
        total += s;
    }
    if (i < N) rowptr[i] = v + woff - orig;
    if (t == 0) bsum[blockIdx.x] = total;
}

__global__ void scan_bsums(const int* __restrict__ bsum, int* __restrict__ bsum2,
                           int* __restrict__ rowptr, int nb, int N) {
    int lane = threadIdx.x;   // 64 threads, nb <= 64
    int v = (lane < nb) ? bsum[lane] : 0;
    int orig = v;
    #pragma unroll
    for (int off = 1; off < 64; off <<= 1) {
        int n = __shfl_up(v, off, 64);
        if (lane >= off) v += n;
    }
    if (lane < nb) bsum2[lane] = v - orig;
    if (lane == 63) rowptr[N] = v;
}

__global__ __launch_bounds__(1024) void scan_add(
        int* __restrict__ rowptr, const int* __restrict__ bsum2, int N) {
    int i = blockIdx.x * 1024 + threadIdx.x;
    if (i < N) rowptr[i] += bsum2[blockIdx.x];
}

// ---------------------------------------------------------------------------
// Scatter: store PRE-SCALED byte offsets (s * 512 = s<<9) so gat_node's
// gather address is a single v_or with the lane's channel-byte offset.
__global__ void scatter_edges(const int* __restrict__ eidx, int E, int N,
                              const int* __restrict__ rowptr,
                              int* __restrict__ fill, int* __restrict__ srcS) {
    int w = blockIdx.x * blockDim.x + threadIdx.x;
    int Etot = E + N;
    if (w >= Etot) return;
    int s, d;
    if (w < E) { s = eidx[w]; d = eidx[E + w]; }
    else       { s = w - E;   d = w - E; }
    int pos = rowptr[d] + atomicAdd(&fill[d], 1);
    srcS[pos] = s << 9;          // byte offset of row s (HC * 2B = 512)
}

// ---------------------------------------------------------------------------
// Fused GATv2 per-node: one wave per dst node. Two edges per wave per step
// (half-waves h=0/1), 8 channels per lane (one dwordx4 gather per lane).
// R8 = R1-EXACT loop body (empirically best: 70.0 us; R2/R3 restructures
// regressed — hand scheduling fought the compiler). Only changes vs R1:
//  * srcB holds pre-scaled BYTE offsets (same op count in the body),
//  * att/bias loads hoisted out of the node loop (lane-only dependent),
//  * persistent grid-stride over nodes (4x fewer block launches, bounded
//    dispatch tail) — outside the hot loop, instruction stream untouched.
// LAYER1: ELU + bf16 SWIZZLED store (feeds layer-2 GEMM DMA); else fp32.
template <int LAYER1>
__global__ __launch_bounds__(256) void gat_node(
        const ushort* __restrict__ xl, const ushort* __restrict__ xr,
        const float* __restrict__ att, const float* __restrict__ bias,
        const int* __restrict__ rowptr, const unsigned* __restrict__ srcB,
        void* __restrict__ outp, int N) {
    int lane = threadIdx.x & 63;
    int h = lane >> 5;                       // which edge of the pair
    int q = lane & 31;                       // 16B-block index within row
    unsigned cb = (unsigned)q * 16u;         // byte offset within row
    const char* xbase = (const char*)xl;

    // node-invariant loads (lane-only): hoisted out of the node loop
    float4 av0 = *(const float4*)(att + q * 8);
    float4 av1 = *(const float4*)(att + q * 8 + 4);
    float4 bv0 = *(const float4*)(bias + q * 8);
    float4 bv1 = *(const float4*)(bias + q * 8 + 4);

    int nodeStride = gridDim.x * 4;
    for (int node = blockIdx.x * 4 + (threadIdx.x >> 6); node < N;
         node += nodeStride) {
        int beg = rowptr[node], end = rowptr[node + 1];

        long long nbase = (long long)node * HC;
        uint4 xu = *(const uint4*)(xr + nbase + q * 8);
        float xr0 = __uint_as_float(xu.x << 16);
        float xr1 = __uint_as_float(xu.x & 0xffff0000u);
        float xr2 = __uint_as_float(xu.y << 16);
        float xr3 = __uint_as_float(xu.y & 0xffff0000u);
        float xr4 = __uint_as_float(xu.z << 16);
        float xr5 = __uint_as_float(xu.z & 0xffff0000u);
        float xr6 = __uint_as_float(xu.w << 16);
        float xr7 = __uint_as_float(xu.w & 0xffff0000u);

        float ssA = 0.f, ssB = 0.f;
        float aA0 = 0.f, aA1 = 0.f, aA2 = 0.f, aA3 = 0.f;
        float aA4 = 0.f, aA5 = 0.f, aA6 = 0.f, aA7 = 0.f;
        float aB0 = 0.f, aB1 = 0.f, aB2 = 0.f, aB3 = 0.f;
        float aB4 = 0.f, aB5 = 0.f, aB6 = 0.f, aB7 = 0.f;

// EDGE2 processes edges (P, P+h): 2 edges per wave. ALLV=0 -> single valid
// edge at P; half-1 lanes clamp to P and contribute ex=0.
#define EDGE2(P, SFX, ALLV)                                                    \
    {                                                                          \
        int pe = (P) + ((ALLV) ? h : 0);                                       \
        unsigned off = srcB[pe] | cb;                                          \
        uint4 dv = *(const uint4*)(xbase + off);                               \
        float v0 = __uint_as_float(dv.x << 16);                                \
        float v1 = __uint_as_float(dv.x & 0xffff0000u);                        \
        float v2 = __uint_as_float(dv.y << 16);                                \
        float v3 = __uint_as_float(dv.y & 0xffff0000u);                        \
        float v4 = __uint_as_float(dv.z << 16);                                \
        float v5 = __uint_as_float(dv.z & 0xffff0000u);                        \
        float v6 = __uint_as_float(dv.w << 16);                                \
        float v7 = __uint_as_float(dv.w & 0xffff0000u);                        \
        float t0 = v0 + xr0, t1 = v1 + xr1, t2 = v2 + xr2, t3 = v3 + xr3;      \
        float t4 = v4 + xr4, t5 = v5 + xr5, t6 = v6 + xr6, t7 = v7 + xr7;      \
        float st = av0.x * t0;                                                 \
        st = fmaf(av0.y, t1, st); st = fmaf(av0.z, t2, st);                    \
        st = fmaf(av0.w, t3, st); st = fmaf(av1.x, t4, st);                    \
        st = fmaf(av1.y, t5, st); st = fmaf(av1.z, t6, st);                    \
        st = fmaf(av1.w, t7, st);                                              \
        float sa = av0.x * fabsf(t0);                                          \
        sa = fmaf(av0.y, fabsf(t1), sa); sa = fmaf(av0.z, fabsf(t2), sa);      \
        sa = fmaf(av0.w, fabsf(t3), sa); sa = fmaf(av1.x, fabsf(t4), sa);      \
        sa = fmaf(av1.y, fabsf(t5), sa); sa = fmaf(av1.z, fabsf(t6), sa);      \
        sa = fmaf(av1.w, fabsf(t7), sa);                                       \
        float sc = fmaf(0.6f, st, 0.4f * sa);                                  \
        sc += __shfl_xor(sc, 1, 64);                                           \
        sc += __shfl_xor(sc, 2, 64);                                           \
        float ex = ((ALLV) || h == 0) ? __expf(sc) : 0.f;                      \
        ss##SFX += ex;                                                         \
        a##SFX##0 = fmaf(ex, v0, a##SFX##0);                                   \
        a##SFX##1 = fmaf(ex, v1, a##SFX##1);                                   \
        a##SFX##2 = fmaf(ex, v2, a##SFX##2);                                   \
        a##SFX##3 = fmaf(ex, v3, a##SFX##3);                                   \
        a##SFX##4 = fmaf(ex, v4, a##SFX##4);                                   \
        a##SFX##5 = fmaf(ex, v5, a##SFX##5);                                   \
        a##SFX##6 = fmaf(ex, v6, a##SFX##6);                                   \
        a##SFX##7 = fmaf(ex, v7, a##SFX##7);                                   \
    }

        int p = beg;
        for (; p + 4 <= end; p += 4) {       // unroll-2: 4 edges in flight
            EDGE2(p, A, 1)
            EDGE2(p + 2, B, 1)
        }
        if (p + 2 <= end) { EDGE2(p, A, 1) p += 2; }
        if (p < end) { EDGE2(p, B, 0) }
#undef EDGE2

        // merge the two half-wave partial sums (once per node)
        float ss = ssA + ssB;
        ss += __shfl_xor(ss, 32, 64);
        float a0 = aA0 + aB0; a0 += __shfl_xor(a0, 32, 64);
        float a1 = aA1 + aB1; a1 += __shfl_xor(a1, 32, 64);
        float a2 = aA2 + aB2; a2 += __shfl_xor(a2, 32, 64);
        float a3 = aA3 + aB3; a3 += __shfl_xor(a3, 32, 64);
        float a4 = aA4 + aB4; a4 += __shfl_xor(a4, 32, 64);
        float a5 = aA5 + aB5; a5 += __shfl_xor(a5, 32, 64);
        float a6 = aA6 + aB6; a6 += __shfl_xor(a6, 32, 64);
        float a7 = aA7 + aB7; a7 += __shfl_xor(a7, 32, 64);

        float inv = 1.f / ss;
        float o0 = fmaf(a0, inv, bv0.x);
        float o1 = fmaf(a1, inv, bv0.y);
        float o2 = fmaf(a2, inv, bv0.z);
        float o3 = fmaf(a3, inv, bv0.w);
        float o4 = fmaf(a4, inv, bv1.x);
        float o5 = fmaf(a5, inv, bv1.y);
        float o6 = fmaf(a6, inv, bv1.z);
        float o7 = fmaf(a7, inv, bv1.w);

        if (LAYER1) {
            // each half stores its 4 channels of the 16B block q
            float s0 = h ? o4 : o0;
            float s1 = h ? o5 : o1;
            float s2 = h ? o6 : o2;
            float s3 = h ? o7 : o3;
            s0 = s0 > 0.f ? s0 : expm1f(s0);
            s1 = s1 > 0.f ? s1 : expm1f(s1);
            s2 = s2 > 0.f ? s2 : expm1f(s2);
            s3 = s3 > 0.f ? s3 : expm1f(s3);
            ushort4 pk;
            pk.x = bf16_rne(s0); pk.y = bf16_rne(s1);
            pk.z = bf16_rne(s2); pk.w = bf16_rne(s3);
            int jx = q ^ (node & 7);         // swizzled 16B-block position
            *(ushort4*)((ushort*)outp + nbase + jx * 8 + h * 4) = pk;
        } else {
            float4 ov = h ? make_float4(o4, o5, o6, o7)
                          : make_float4(o0, o1, o2, o3);
            *(float4*)((float*)outp + nbase + q * 8 + h * 4) = ov;
        }
    }
}

// ---------------------------------------------------------------------------
extern "C" void kernel_launch(void* const* d_in, const int* in_sizes, int n_in,
                              void* d_out, int out_size, void* d_ws, size_t ws_size,
                              hipStream_t stream) {
    const float* x    = (const float*)d_in[0];
    const int*   eidx = (const int*)d_in[1];
    const float* Wl1  = (const float*)d_in[2];
    const float* Wr1  = (const float*)d_in[3];
    const float* att1 = (const float*)d_in[4];
    const float* b1   = (const float*)d_in[5];
    const float* Wl2  = (const float*)d_in[6];
    const float* Wr2  = (const float*)d_in[7];
    const float* att2 = (const float*)d_in[8];
    const float* b2   = (const float*)d_in[9];
    float* out = (float*)d_out;

    const int N = in_sizes[0] / HC;       // 50000
    const int E = in_sizes[1] / 2;        // 800000
    const int Etot = E + N;
    const long long NHC = (long long)N * HC;

    // workspace layout (16B-aligned bf16 region first)
    ushort* xl   = (ushort*)d_ws;         // N*HC bf16 (plain)
    ushort* xr   = xl + NHC;              // N*HC     (plain)
    ushort* hbuf = xr + NHC;              // N*HC     (swizzled)
    ushort* xb   = hbuf + NHC;            // N*HC     (swizzled)
    ushort* wt1  = xb + NHC;              // 512*HC   (swizzled)
    ushort* wt2  = wt1 + 512 * HC;        // 512*HC   (swizzled)
    int* rowptr  = (int*)(wt2 + 512 * HC);// N+1
    int* counts  = rowptr + (N + 1);      // N
    int* fill    = counts + N;            // N (contiguous with counts)
    int* bsum    = fill + N;              // 64
    int* bsum2   = bsum + 64;             // 64
    int* srcS    = bsum2 + 64;            // Etot

    const int TB = 256;
    dim3 blk(TB);
    int gEdgesT = (Etot + TB - 1) / TB;
    int mtTiles = (N + 63) / 64;                  // 782
    int gGemm   = ((mtTiles + 15) / 16) * 128;    // supergrouped (16 mt x 8 nt)
    int gNode   = 3136;                   // persistent: 4 nodes/block/iter
    int nb      = (N + 1023) / 1024;      // 49 <= 64
    long long nblk = NHC / 8;
    int gCvt    = (int)((nblk + TB - 1) / TB);

    // ---- one-time conversions + CSR build ----
    cvt_bf16_sw<<<gCvt, blk, 0, stream>>>(x, xb, nblk);
    build_wt<<<512, blk, 0, stream>>>(Wl1, Wr1, wt1);
    build_wt<<<512, blk, 0, stream>>>(Wl2, Wr2, wt2);
    hipMemsetAsync(counts, 0, (size_t)2 * N * sizeof(int), stream);
    hist_dst<<<gEdgesT, blk, 0, stream>>>(eidx, E, N, counts);
    scan_local<<<nb, 1024, 0, stream>>>(counts, rowptr, bsum, N);
    scan_bsums<<<1, 64, 0, stream>>>(bsum, bsum2, rowptr, nb, N);
    scan_add<<<nb, 1024, 0, stream>>>(rowptr, bsum2, N);
    scatter_edges<<<gEdgesT, blk, 0, stream>>>(eidx, E, N, rowptr, fill, srcS);

    // ================= layer 1 =================
    gemm_mfma<<<gGemm, blk, 0, stream>>>(xb, wt1, xl, xr, N);
    gat_node<1><<<gNode, blk, 0, stream>>>(xl, xr, att1, b1, rowptr,
                                           (const unsigned*)srcS, hbuf, N);

    // ================= layer 2 =================
    gemm_mfma<<<gGemm, blk, 0, stream>>>(hbuf, wt2, xl, xr, N);
    gat_node<0><<<gNode, blk, 0, stream>>>(xl, xr, att2, b2, rowptr,
                                           (const unsigned*)srcS, out, N);
}

// Round 5
// 407.692 us; speedup vs baseline: 1.0618x; 1.0571x over previous
//
#include <hip/hip_runtime.h>
#include <hip/hip_bf16.h>
#include <math.h>

// Problem constants (match reference)
#define HEADS 8
#define HC 256            // HEADS*CHAN = D
#define NEG_SLOPE 0.2f    // leaky(t) = 0.6*t + 0.4*|t|

typedef __attribute__((ext_vector_type(8))) short short8;
typedef __attribute__((ext_vector_type(16))) float floatx16;

__device__ inline ushort bf16_rne(float f) {
    unsigned u = __float_as_uint(f);
    return (ushort)((u + 0x7FFFu + ((u >> 16) & 1u)) >> 16);
}

// ---------------------------------------------------------------------------
// fp32 -> bf16 convert of x with XOR-swizzled layout: 16B block j of row r
// stored at block position j ^ (r&7). XOR only permutes within 8-block
// (128B) groups, so any 64-col K-slice stays self-contained (GEMM relies
// on this for per-slice staging).
__global__ __launch_bounds__(256) void cvt_bf16_sw(
        const float* __restrict__ x, ushort* __restrict__ xb, long long nblk) {
    long long id = (long long)blockIdx.x * blockDim.x + threadIdx.x;
    if (id >= nblk) return;
    long long r = id >> 5;
    int j = (int)(id & 31);
    const float4* p = (const float4*)(x + id * 8);
    float4 a = p[0], b = p[1];
    short8 pk;
    pk[0] = (short)bf16_rne(a.x); pk[1] = (short)bf16_rne(a.y);
    pk[2] = (short)bf16_rne(a.z); pk[3] = (short)bf16_rne(a.w);
    pk[4] = (short)bf16_rne(b.x); pk[5] = (short)bf16_rne(b.y);
    pk[6] = (short)bf16_rne(b.z); pk[7] = (short)bf16_rne(b.w);
    int jx = j ^ ((int)r & 7);
    *(short8*)(xb + r * 256 + jx * 8) = pk;
}

// ---------------------------------------------------------------------------
// Pre-transpose weights into wt[n][k] bf16, same XOR swizzle (row = n).
__global__ __launch_bounds__(256) void build_wt(
        const float* __restrict__ Wl, const float* __restrict__ Wr,
        ushort* __restrict__ wt) {
    int n = blockIdx.x;            // 0..511
    int k = threadIdx.x;           // 0..255
    const float* W = (n < 256) ? Wl : Wr;
    int col = n & 255;
    int jx = (k >> 3) ^ (n & 7);
    wt[n * HC + jx * 8 + (k & 7)] = bf16_rne(W[k * HC + col]);
}

// ---------------------------------------------------------------------------
// MFMA dual-GEMM: C[N,512] = A[N,256](bf16,swz) x wt(bf16,swz), bf16 out.
// R9: 128x128 C-tile, K sliced 4x64, double-buffered LDS (2x32KB = 64KB ->
// 2 blocks/CU). Staged DMA traffic halves vs 64x64 (200 MB vs 400 MB) and
// stage(k+1) is issued BEFORE compute(k) so DMA overlaps MFMA. Each DMA
// issue stages 8 rows x 128B (per-lane strided global src, linear LDS dst).
// Supergroup of 32 (8 mt x 4 nt): the 4 nt-copies of an mt share bid low-3
// bits (same XCD under round-robin) -> A slice L2-hits after first touch.
// 4 waves, each a 64x64 quadrant = 2x2 mfma_32x32x16_bf16 tiles.
__global__ __launch_bounds__(256) void gemm_mfma(
        const ushort* __restrict__ A, const ushort* __restrict__ wt,
        ushort* __restrict__ xl, ushort* __restrict__ xr, int N) {
    __shared__ ushort lA[2][128 * 64];
    __shared__ ushort lB[2][128 * 64];
    int mtT = (N + 127) >> 7;           // 391
    int local = blockIdx.x & 31;
    int grp   = blockIdx.x >> 5;
    int mt = grp * 8 + (local & 7);
    int nt = local >> 3;                // 0..3 (128-col slices of 512)
    if (mt >= mtT) return;              // uniform per block, before barriers
    int m0 = mt * 128, n0 = nt * 128;
    int t = threadIdx.x;
    int lane = t & 63, wv = t >> 6;

    // per-lane global byte offset within an 8-row x 128B chunk
    int gOff = (lane >> 3) * 512 + (lane & 7) * 16;
    const char* gA = (const char*)A + (long long)m0 * 512;
    const char* gB = (const char*)wt + (long long)n0 * 512;

#define STAGE(BUF, KS)                                                         \
    {                                                                          \
        _Pragma("unroll")                                                      \
        for (int i_ = 0; i_ < 4; ++i_) {                                       \
            int rr = wv * 32 + i_ * 8;                                         \
            __builtin_amdgcn_global_load_lds(                                  \
                (const __attribute__((address_space(1))) unsigned int*)        \
                    (gA + (long long)rr * 512 + (KS) * 128 + gOff),            \
                (__attribute__((address_space(3))) unsigned int*)              \
                    (&lA[BUF][rr * 64]), 16, 0, 0);                            \
            __builtin_amdgcn_global_load_lds(                                  \
                (const __attribute__((address_space(1))) unsigned int*)        \
                    (gB + (long long)rr * 512 + (KS) * 128 + gOff),            \
                (__attribute__((address_space(3))) unsigned int*)              \
                    (&lB[BUF][rr * 64]), 16, 0, 0);                            \
        }                                                                      \
    }

    int rA0 = (wv & 1) * 64 + (lane & 31);
    int rB0 = (wv >> 1) * 64 + (lane & 31);
    int kh = lane >> 5;                 // k-half of the fragment
    int sA = rA0 & 7, sB = rB0 & 7;     // (r+32)&7 is identical
    floatx16 ac00, ac01, ac10, ac11;
    #pragma unroll
    for (int i = 0; i < 16; ++i) { ac00[i] = 0.f; ac01[i] = 0.f;
                                   ac10[i] = 0.f; ac11[i] = 0.f; }

    STAGE(0, 0)
    __syncthreads();
    int buf = 0;
    #pragma unroll
    for (int ks = 0; ks < 4; ++ks) {
        if (ks < 3) STAGE(buf ^ 1, ks + 1)
        #pragma unroll
        for (int kk = 0; kk < 4; ++kk) {
            int jb = kk * 2 + kh;       // 16B k-block within the slice
            short8 a0 = *(const short8*)&lA[buf][rA0 * 64 + ((jb ^ sA) * 8)];
            short8 a1 = *(const short8*)&lA[buf][(rA0 + 32) * 64 + ((jb ^ sA) * 8)];
            short8 b0 = *(const short8*)&lB[buf][rB0 * 64 + ((jb ^ sB) * 8)];
            short8 b1 = *(const short8*)&lB[buf][(rB0 + 32) * 64 + ((jb ^ sB) * 8)];
            ac00 = __builtin_amdgcn_mfma_f32_32x32x16_bf16(a0, b0, ac00, 0, 0, 0);
            ac01 = __builtin_amdgcn_mfma_f32_32x32x16_bf16(a0, b1, ac01, 0, 0, 0);
            ac10 = __builtin_amdgcn_mfma_f32_32x32x16_bf16(a1, b0, ac10, 0, 0, 0);
            ac11 = __builtin_amdgcn_mfma_f32_32x32x16_bf16(a1, b1, ac11, 0, 0, 0);
        }
        __syncthreads();                // drains vmcnt for next buf too
        buf ^= 1;
    }
#undef STAGE

    // ---- epilogue: C/D layout col=lane&31, row=(reg&3)+8*(reg>>2)+4*kh ----
    ushort* obase = (nt < 2) ? xl : xr;               // xl/xr PLAIN layout
    int colb = (nt & 1) * 128 + (wv >> 1) * 64 + (lane & 31);
    int rbase = m0 + (wv & 1) * 64 + 4 * kh;
    #pragma unroll
    for (int g = 0; g < 4; ++g) {
        #pragma unroll
        for (int q = 0; q < 4; ++q) {
            int row0 = rbase + q + 8 * g;
            int row1 = row0 + 32;
            int e = g * 4 + q;
            if (row0 < N) {
                obase[(long long)row0 * HC + colb]      = bf16_rne(ac00[e]);
                obase[(long long)row0 * HC + colb + 32] = bf16_rne(ac01[e]);
            }
            if (row1 < N) {
                obase[(long long)row1 * HC + colb]      = bf16_rne(ac10[e]);
                obase[(long long)row1 * HC + colb + 32] = bf16_rne(ac11[e]);
            }
        }
    }
}

// ---------------------------------------------------------------------------
// Histogram of dst (self-loops appended implicitly: edge w>=E is node w-E)
__global__ void hist_dst(const int* __restrict__ eidx, int E, int N,
                         int* __restrict__ counts) {
    int w = blockIdx.x * blockDim.x + threadIdx.x;
    int Etot = E + N;
    if (w >= Etot) return;
    int d = (w < E) ? eidx[E + w] : (w - E);
    atomicAdd(&counts[d], 1);
}

// ---------------------------------------------------------------------------
// 3-kernel exclusive scan: per-block scan -> block-sum scan -> add offsets
__global__ __launch_bounds__(1024) void scan_local(
        const int* __restrict__ counts, int* __restrict__ rowptr,
        int* __restrict__ bsum, int N) {
    __shared__ int wsums[16];
    int t = threadIdx.x, lane = t & 63, wv = t >> 6;
    int i = blockIdx.x * 1024 + t;
    int v = (i < N) ? counts[i] : 0;
    int orig = v;
    #pragma unroll
    for (int off = 1; off < 64; off <<= 1) {
        int n = __shfl_up(v, off, 64);
        if (lane >= off) v += n;
    }
    if (lane == 63) wsums[wv] = v;
    __syncthreads();
    int woff = 0, total = 0;
    #pragma unroll
    for (int w_ = 0; w_ < 16; ++w_) {
        int s = wsums[w_];
        if (w_ < wv) woff += s;
        total += s;
    }
    if (i < N) rowptr[i] = v + woff - orig;
    if (t == 0) bsum[blockIdx.x] = total;
}

__global__ void scan_bsums(const int* __restrict__ bsum, int* __restrict__ bsum2,
                           int* __restrict__ rowptr, int nb, int N) {
    int lane = threadIdx.x;   // 64 threads, nb <= 64
    int v = (lane < nb) ? bsum[lane] : 0;
    int orig = v;
    #pragma unroll
    for (int off = 1; off < 64; off <<= 1) {
        int n = __shfl_up(v, off, 64);
        if (lane >= off) v += n;
    }
    if (lane < nb) bsum2[lane] = v - orig;
    if (lane == 63) rowptr[N] = v;
}

__global__ __launch_bounds__(1024) void scan_add(
        int* __restrict__ rowptr, const int* __restrict__ bsum2, int N) {
    int i = blockIdx.x * 1024 + threadIdx.x;
    if (i < N) rowptr[i] += bsum2[blockIdx.x];
}

// ---------------------------------------------------------------------------
// Scatter: store PRE-SCALED byte offsets (s * 512 = s<<9) so gat_node's
// gather address is a single v_or with the lane's channel-byte offset.
__global__ void scatter_edges(const int* __restrict__ eidx, int E, int N,
                              const int* __restrict__ rowptr,
                              int* __restrict__ fill, int* __restrict__ srcS) {
    int w = blockIdx.x * blockDim.x + threadIdx.x;
    int Etot = E + N;
    if (w >= Etot) return;
    int s, d;
    if (w < E) { s = eidx[w]; d = eidx[E + w]; }
    else       { s = w - E;   d = w - E; }
    int pos = rowptr[d] + atomicAdd(&fill[d], 1);
    srcS[pos] = s << 9;          // byte offset of row s (HC * 2B = 512)
}

// ---------------------------------------------------------------------------
// Fused GATv2 per-node: one wave per dst node, ONE-SHOT blocks (4 nodes per
// 256-block). This is the measured-best R1 structure (70.0 us) verbatim —
// R2/R3/R4 restructures (rotation pipeline, hoisted gathers, persistent
// grid) all regressed: occupancy/load-balance beat hand scheduling here.
// Only delta vs R1: srcB holds pre-scaled byte offsets (or+byte-add replaces
// shl+or+scale in the same instruction stream).
// Two edges per wave per step (half-waves h=0/1), 8 channels per lane.
// LAYER1: ELU + bf16 SWIZZLED store (feeds layer-2 GEMM DMA); else fp32.
template <int LAYER1>
__global__ __launch_bounds__(256) void gat_node(
        const ushort* __restrict__ xl, const ushort* __restrict__ xr,
        const float* __restrict__ att, const float* __restrict__ bias,
        const int* __restrict__ rowptr, const unsigned* __restrict__ srcB,
        void* __restrict__ outp, int N) {
    int node = blockIdx.x * 4 + (threadIdx.x >> 6);
    int lane = threadIdx.x & 63;
    if (node >= N) return;
    int h = lane >> 5;                       // which edge of the pair
    int q = lane & 31;                       // 16B-block index within row
    unsigned cb = (unsigned)q * 16u;         // byte offset within row
    const char* xbase = (const char*)xl;
    int beg = rowptr[node], end = rowptr[node + 1];

    long long nbase = (long long)node * HC;
    uint4 xu = *(const uint4*)(xr + nbase + q * 8);
    float xr0 = __uint_as_float(xu.x << 16);
    float xr1 = __uint_as_float(xu.x & 0xffff0000u);
    float xr2 = __uint_as_float(xu.y << 16);
    float xr3 = __uint_as_float(xu.y & 0xffff0000u);
    float xr4 = __uint_as_float(xu.z << 16);
    float xr5 = __uint_as_float(xu.z & 0xffff0000u);
    float xr6 = __uint_as_float(xu.w << 16);
    float xr7 = __uint_as_float(xu.w & 0xffff0000u);
    float4 av0 = *(const float4*)(att + q * 8);
    float4 av1 = *(const float4*)(att + q * 8 + 4);

    float ssA = 0.f, ssB = 0.f;
    float aA0 = 0.f, aA1 = 0.f, aA2 = 0.f, aA3 = 0.f;
    float aA4 = 0.f, aA5 = 0.f, aA6 = 0.f, aA7 = 0.f;
    float aB0 = 0.f, aB1 = 0.f, aB2 = 0.f, aB3 = 0.f;
    float aB4 = 0.f, aB5 = 0.f, aB6 = 0.f, aB7 = 0.f;

// EDGE2 processes edges (P, P+h): 2 edges per wave. ALLV=0 -> single valid
// edge at P; half-1 lanes clamp to P and contribute ex=0.
#define EDGE2(P, SFX, ALLV)                                                    \
    {                                                                          \
        int pe = (P) + ((ALLV) ? h : 0);                                       \
        unsigned off = srcB[pe] | cb;                                          \
        uint4 dv = *(const uint4*)(xbase + off);                               \
        float v0 = __uint_as_float(dv.x << 16);                                \
        float v1 = __uint_as_float(dv.x & 0xffff0000u);                        \
        float v2 = __uint_as_float(dv.y << 16);                                \
        float v3 = __uint_as_float(dv.y & 0xffff0000u);                        \
        float v4 = __uint_as_float(dv.z << 16);                                \
        float v5 = __uint_as_float(dv.z & 0xffff0000u);                        \
        float v6 = __uint_as_float(dv.w << 16);                                \
        float v7 = __uint_as_float(dv.w & 0xffff0000u);                        \
        float t0 = v0 + xr0, t1 = v1 + xr1, t2 = v2 + xr2, t3 = v3 + xr3;      \
        float t4 = v4 + xr4, t5 = v5 + xr5, t6 = v6 + xr6, t7 = v7 + xr7;      \
        float st = av0.x * t0;                                                 \
        st = fmaf(av0.y, t1, st); st = fmaf(av0.z, t2, st);                    \
        st = fmaf(av0.w, t3, st); st = fmaf(av1.x, t4, st);                    \
        st = fmaf(av1.y, t5, st); st = fmaf(av1.z, t6, st);                    \
        st = fmaf(av1.w, t7, st);                                              \
        float sa = av0.x * fabsf(t0);                                          \
        sa = fmaf(av0.y, fabsf(t1), sa); sa = fmaf(av0.z, fabsf(t2), sa);      \
        sa = fmaf(av0.w, fabsf(t3), sa); sa = fmaf(av1.x, fabsf(t4), sa);      \
        sa = fmaf(av1.y, fabsf(t5), sa); sa = fmaf(av1.z, fabsf(t6), sa);      \
        sa = fmaf(av1.w, fabsf(t7), sa);                                       \
        float sc = fmaf(0.6f, st, 0.4f * sa);                                  \
        sc += __shfl_xor(sc, 1, 64);                                           \
        sc += __shfl_xor(sc, 2, 64);                                           \
        float ex = ((ALLV) || h == 0) ? __expf(sc) : 0.f;                      \
        ss##SFX += ex;                                                         \
        a##SFX##0 = fmaf(ex, v0, a##SFX##0);                                   \
        a##SFX##1 = fmaf(ex, v1, a##SFX##1);                                   \
        a##SFX##2 = fmaf(ex, v2, a##SFX##2);                                   \
        a##SFX##3 = fmaf(ex, v3, a##SFX##3);                                   \
        a##SFX##4 = fmaf(ex, v4, a##SFX##4);                                   \
        a##SFX##5 = fmaf(ex, v5, a##SFX##5);                                   \
        a##SFX##6 = fmaf(ex, v6, a##SFX##6);                                   \
        a##SFX##7 = fmaf(ex, v7, a##SFX##7);                                   \
    }

    int p = beg;
    for (; p + 4 <= end; p += 4) {           // unroll-2: 4 edges in flight
        EDGE2(p, A, 1)
        EDGE2(p + 2, B, 1)
    }
    if (p + 2 <= end) { EDGE2(p, A, 1) p += 2; }
    if (p < end) { EDGE2(p, B, 0) }
#undef EDGE2

    // merge the two half-wave partial sums (once per node)
    float ss = ssA + ssB;
    ss += __shfl_xor(ss, 32, 64);
    float a0 = aA0 + aB0; a0 += __shfl_xor(a0, 32, 64);
    float a1 = aA1 + aB1; a1 += __shfl_xor(a1, 32, 64);
    float a2 = aA2 + aB2; a2 += __shfl_xor(a2, 32, 64);
    float a3 = aA3 + aB3; a3 += __shfl_xor(a3, 32, 64);
    float a4 = aA4 + aB4; a4 += __shfl_xor(a4, 32, 64);
    float a5 = aA5 + aB5; a5 += __shfl_xor(a5, 32, 64);
    float a6 = aA6 + aB6; a6 += __shfl_xor(a6, 32, 64);
    float a7 = aA7 + aB7; a7 += __shfl_xor(a7, 32, 64);

    float inv = 1.f / ss;
    float4 bv0 = *(const float4*)(bias + q * 8);
    float4 bv1 = *(const float4*)(bias + q * 8 + 4);
    float o0 = fmaf(a0, inv, bv0.x);
    float o1 = fmaf(a1, inv, bv0.y);
    float o2 = fmaf(a2, inv, bv0.z);
    float o3 = fmaf(a3, inv, bv0.w);
    float o4 = fmaf(a4, inv, bv1.x);
    float o5 = fmaf(a5, inv, bv1.y);
    float o6 = fmaf(a6, inv, bv1.z);
    float o7 = fmaf(a7, inv, bv1.w);

    if (LAYER1) {
        // each half stores its 4 channels of the 16B block q
        float s0 = h ? o4 : o0;
        float s1 = h ? o5 : o1;
        float s2 = h ? o6 : o2;
        float s3 = h ? o7 : o3;
        s0 = s0 > 0.f ? s0 : expm1f(s0);
        s1 = s1 > 0.f ? s1 : expm1f(s1);
        s2 = s2 > 0.f ? s2 : expm1f(s2);
        s3 = s3 > 0.f ? s3 : expm1f(s3);
        ushort4 pk;
        pk.x = bf16_rne(s0); pk.y = bf16_rne(s1);
        pk.z = bf16_rne(s2); pk.w = bf16_rne(s3);
        int jx = q ^ (node & 7);             // swizzled 16B-block position
        *(ushort4*)((ushort*)outp + nbase + jx * 8 + h * 4) = pk;
    } else {
        float4 ov = h ? make_float4(o4, o5, o6, o7)
                      : make_float4(o0, o1, o2, o3);
        *(float4*)((float*)outp + nbase + q * 8 + h * 4) = ov;
    }
}

// ---------------------------------------------------------------------------
extern "C" void kernel_launch(void* const* d_in, const int* in_sizes, int n_in,
                              void* d_out, int out_size, void* d_ws, size_t ws_size,
                              hipStream_t stream) {
    const float* x    = (const float*)d_in[0];
    const int*   eidx = (const int*)d_in[1];
    const float* Wl1  = (const float*)d_in[2];
    const float* Wr1  = (const float*)d_in[3];
    const float* att1 = (const float*)d_in[4];
    const float* b1   = (const float*)d_in[5];
    const float* Wl2  = (const float*)d_in[6];
    const float* Wr2  = (const float*)d_in[7];
    const float* att2 = (const float*)d_in[8];
    const float* b2   = (const float*)d_in[9];
    float* out = (float*)d_out;

    const int N = in_sizes[0] / HC;       // 50000
    const int E = in_sizes[1] / 2;        // 800000
    const int Etot = E + N;
    const long long NHC = (long long)N * HC;

    // workspace layout (16B-aligned bf16 region first)
    ushort* xl   = (ushort*)d_ws;         // N*HC bf16 (plain)
    ushort* xr   = xl + NHC;              // N*HC     (plain)
    ushort* hbuf = xr + NHC;              // N*HC     (swizzled)
    ushort* xb   = hbuf + NHC;            // N*HC     (swizzled)
    ushort* wt1  = xb + NHC;              // 512*HC   (swizzled)
    ushort* wt2  = wt1 + 512 * HC;        // 512*HC   (swizzled)
    int* rowptr  = (int*)(wt2 + 512 * HC);// N+1
    int* counts  = rowptr + (N + 1);      // N
    int* fill    = counts + N;            // N (contiguous with counts)
    int* bsum    = fill + N;              // 64
    int* bsum2   = bsum + 64;             // 64
    int* srcS    = bsum2 + 64;            // Etot

    const int TB = 256;
    dim3 blk(TB);
    int gEdgesT = (Etot + TB - 1) / TB;
    int mtTiles = (N + 127) / 128;                // 391
    int gGemm   = ((mtTiles + 7) / 8) * 32;       // supergrouped (8 mt x 4 nt)
    int gNode   = (N + 3) / 4;
    int nb      = (N + 1023) / 1024;      // 49 <= 64
    long long nblk = NHC / 8;
    int gCvt    = (int)((nblk + TB - 1) / TB);

    // ---- one-time conversions + CSR build ----
    cvt_bf16_sw<<<gCvt, blk, 0, stream>>>(x, xb, nblk);
    build_wt<<<512, blk, 0, stream>>>(Wl1, Wr1, wt1);
    build_wt<<<512, blk, 0, stream>>>(Wl2, Wr2, wt2);
    hipMemsetAsync(counts, 0, (size_t)2 * N * sizeof(int), stream);
    hist_dst<<<gEdgesT, blk, 0, stream>>>(eidx, E, N, counts);
    scan_local<<<nb, 1024, 0, stream>>>(counts, rowptr, bsum, N);
    scan_bsums<<<1, 64, 0, stream>>>(bsum, bsum2, rowptr, nb, N);
    scan_add<<<nb, 1024, 0, stream>>>(rowptr, bsum2, N);
    scatter_edges<<<gEdgesT, blk, 0, stream>>>(eidx, E, N, rowptr, fill, srcS);

    // ================= layer 1 =================
    gemm_mfma<<<gGemm, blk, 0, stream>>>(xb, wt1, xl, xr, N);
    gat_node<1><<<gNode, blk, 0, stream>>>(xl, xr, att1, b1, rowptr,
                                           (const unsigned*)srcS, hbuf, N);

    // ================= layer 2 =================
    gemm_mfma<<<gGemm, blk, 0, stream>>>(hbuf, wt2, xl, xr, N);
    gat_node<0><<<gNode, blk, 0, stream>>>(xl, xr, att2, b2, rowptr,
                                           (const unsigned*)srcS, out, N);
}

// Round 7
// 390.446 us; speedup vs baseline: 1.1087x; 1.0442x over previous
//
#include <hip/hip_runtime.h>
#include <hip/hip_bf16.h>
#include <math.h>

// Problem constants (match reference)
#define HEADS 8
#define HC 256            // HEADS*CHAN = D
#define NEG_SLOPE 0.2f    // leaky(t) = 0.6*t + 0.4*|t|

typedef __attribute__((ext_vector_type(8))) short short8;
typedef __attribute__((ext_vector_type(16))) float floatx16;

__device__ inline ushort bf16_rne(float f) {
    unsigned u = __float_as_uint(f);
    return (ushort)((u + 0x7FFFu + ((u >> 16) & 1u)) >> 16);
}

// ---------------------------------------------------------------------------
// fp32 -> bf16 convert of x with XOR-swizzled layout: 16B block j of row r
// stored at block position j ^ (r&7). XOR only permutes within 8-block
// (128B) groups, so any 64-col K-slice stays self-contained (GEMM relies
// on this for per-slice staging).
__global__ __launch_bounds__(256) void cvt_bf16_sw(
        const float* __restrict__ x, ushort* __restrict__ xb, long long nblk) {
    long long id = (long long)blockIdx.x * blockDim.x + threadIdx.x;
    if (id >= nblk) return;
    long long r = id >> 5;
    int j = (int)(id & 31);
    const float4* p = (const float4*)(x + id * 8);
    float4 a = p[0], b = p[1];
    short8 pk;
    pk[0] = (short)bf16_rne(a.x); pk[1] = (short)bf16_rne(a.y);
    pk[2] = (short)bf16_rne(a.z); pk[3] = (short)bf16_rne(a.w);
    pk[4] = (short)bf16_rne(b.x); pk[5] = (short)bf16_rne(b.y);
    pk[6] = (short)bf16_rne(b.z); pk[7] = (short)bf16_rne(b.w);
    int jx = j ^ ((int)r & 7);
    *(short8*)(xb + r * 256 + jx * 8) = pk;
}

// ---------------------------------------------------------------------------
// Pre-transpose weights into wt[n][k] bf16, same XOR swizzle (row = n).
__global__ __launch_bounds__(256) void build_wt(
        const float* __restrict__ Wl, const float* __restrict__ Wr,
        ushort* __restrict__ wt) {
    int n = blockIdx.x;            // 0..511
    int k = threadIdx.x;           // 0..255
    const float* W = (n < 256) ? Wl : Wr;
    int col = n & 255;
    int jx = (k >> 3) ^ (n & 7);
    wt[n * HC + jx * 8 + (k & 7)] = bf16_rne(W[k * HC + col]);
}

// ---------------------------------------------------------------------------
// MFMA dual-GEMM: C[N,512] = A[N,256](bf16,swz) x wt(bf16,swz), bf16 out.
// R11: 128x128 C-tile, K sliced 4x64, SINGLE-buffered 32KB LDS -> 5
// blocks/CU (20 waves). R9/R5's 64KB double-buffer capped residency at 2
// blocks/CU; the per-phase DMA drain (~1200cy vs ~300cy compute) had no TLP
// cover -> CU mostly idle. Staging/read indexing identical to the verified
// R5 kernel (only the buf dimension removed).
// Supergroup of 32 (8 mt x 4 nt): nt-copies of an mt share bid low-3 bits
// (same XCD under round-robin) -> A slice L2-hits after first touch.
// 4 waves, each a 64x64 quadrant = 2x2 mfma_32x32x16_bf16 tiles.
__global__ __launch_bounds__(256) void gemm_mfma(
        const ushort* __restrict__ A, const ushort* __restrict__ wt,
        ushort* __restrict__ xl, ushort* __restrict__ xr, int N) {
    __shared__ ushort lA[128 * 64];
    __shared__ ushort lB[128 * 64];
    int mtT = (N + 127) >> 7;           // 391
    int local = blockIdx.x & 31;
    int grp   = blockIdx.x >> 5;
    int mt = grp * 8 + (local & 7);
    int nt = local >> 3;                // 0..3 (128-col slices of 512)
    if (mt >= mtT) return;              // uniform per block, before barriers
    int m0 = mt * 128, n0 = nt * 128;
    int t = threadIdx.x;
    int lane = t & 63, wv = t >> 6;

    // per-lane global byte offset within an 8-row x 128B chunk
    int gOff = (lane >> 3) * 512 + (lane & 7) * 16;
    const char* gA = (const char*)A + (long long)m0 * 512;
    const char* gB = (const char*)wt + (long long)n0 * 512;

#define STAGE(KS)                                                              \
    {                                                                          \
        _Pragma("unroll")                                                      \
        for (int i_ = 0; i_ < 4; ++i_) {                                       \
            int rr = wv * 32 + i_ * 8;                                         \
            __builtin_amdgcn_global_load_lds(                                  \
                (const __attribute__((address_space(1))) unsigned int*)        \
                    (gA + (long long)rr * 512 + (KS) * 128 + gOff),            \
                (__attribute__((address_space(3))) unsigned int*)              \
                    (&lA[rr * 64]), 16, 0, 0);                                 \
            __builtin_amdgcn_global_load_lds(                                  \
                (const __attribute__((address_space(1))) unsigned int*)        \
                    (gB + (long long)rr * 512 + (KS) * 128 + gOff),            \
                (__attribute__((address_space(3))) unsigned int*)              \
                    (&lB[rr * 64]), 16, 0, 0);                                 \
        }                                                                      \
    }

    int rA0 = (wv & 1) * 64 + (lane & 31);
    int rB0 = (wv >> 1) * 64 + (lane & 31);
    int kh = lane >> 5;                 // k-half of the fragment
    int sA = rA0 & 7, sB = rB0 & 7;     // (r+32)&7 is identical
    floatx16 ac00, ac01, ac10, ac11;
    #pragma unroll
    for (int i = 0; i < 16; ++i) { ac00[i] = 0.f; ac01[i] = 0.f;
                                   ac10[i] = 0.f; ac11[i] = 0.f; }

    #pragma unroll
    for (int ks = 0; ks < 4; ++ks) {
        STAGE(ks)
        __syncthreads();                // drains vmcnt(0): LDS ready
        #pragma unroll
        for (int kk = 0; kk < 4; ++kk) {
            int jb = kk * 2 + kh;       // 16B k-block within the slice
            short8 a0 = *(const short8*)&lA[rA0 * 64 + ((jb ^ sA) * 8)];
            short8 a1 = *(const short8*)&lA[(rA0 + 32) * 64 + ((jb ^ sA) * 8)];
            short8 b0 = *(const short8*)&lB[rB0 * 64 + ((jb ^ sB) * 8)];
            short8 b1 = *(const short8*)&lB[(rB0 + 32) * 64 + ((jb ^ sB) * 8)];
            ac00 = __builtin_amdgcn_mfma_f32_32x32x16_bf16(a0, b0, ac00, 0, 0, 0);
            ac01 = __builtin_amdgcn_mfma_f32_32x32x16_bf16(a0, b1, ac01, 0, 0, 0);
            ac10 = __builtin_amdgcn_mfma_f32_32x32x16_bf16(a1, b0, ac10, 0, 0, 0);
            ac11 = __builtin_amdgcn_mfma_f32_32x32x16_bf16(a1, b1, ac11, 0, 0, 0);
        }
        __syncthreads();                // all ds_reads done before next STAGE
    }
#undef STAGE

    // ---- epilogue: C/D layout col=lane&31, row=(reg&3)+8*(reg>>2)+4*kh ----
    ushort* obase = (nt < 2) ? xl : xr;               // xl/xr PLAIN layout
    int colb = (nt & 1) * 128 + (wv >> 1) * 64 + (lane & 31);
    int rbase = m0 + (wv & 1) * 64 + 4 * kh;
    #pragma unroll
    for (int g = 0; g < 4; ++g) {
        #pragma unroll
        for (int q = 0; q < 4; ++q) {
            int row0 = rbase + q + 8 * g;
            int row1 = row0 + 32;
            int e = g * 4 + q;
            if (row0 < N) {
                obase[(long long)row0 * HC + colb]      = bf16_rne(ac00[e]);
                obase[(long long)row0 * HC + colb + 32] = bf16_rne(ac01[e]);
            }
            if (row1 < N) {
                obase[(long long)row1 * HC + colb]      = bf16_rne(ac10[e]);
                obase[(long long)row1 * HC + colb + 32] = bf16_rne(ac11[e]);
            }
        }
    }
}

// ---------------------------------------------------------------------------
// Histogram of dst (self-loops appended implicitly: edge w>=E is node w-E)
__global__ void hist_dst(const int* __restrict__ eidx, int E, int N,
                         int* __restrict__ counts) {
    int w = blockIdx.x * blockDim.x + threadIdx.x;
    int Etot = E + N;
    if (w >= Etot) return;
    int d = (w < E) ? eidx[E + w] : (w - E);
    atomicAdd(&counts[d], 1);
}

// ---------------------------------------------------------------------------
// 3-kernel exclusive scan: per-block scan -> block-sum scan -> add offsets
__global__ __launch_bounds__(1024) void scan_local(
        const int* __restrict__ counts, int* __restrict__ rowptr,
        int* __restrict__ bsum, int N) {
    __shared__ int wsums[16];
    int t = threadIdx.x, lane = t & 63, wv = t >> 6;
    int i = blockIdx.x * 1024 + t;
    int v = (i < N) ? counts[i] : 0;
    int orig = v;
    #pragma unroll
    for (int off = 1; off < 64; off <<= 1) {
        int n = __shfl_up(v, off, 64);
        if (lane >= off) v += n;
    }
    if (lane == 63) wsums[wv] = v;
    __syncthreads();
    int woff = 0, total = 0;
    #pragma unroll
    for (int w_ = 0; w_ < 16; ++w_) {
        int s = wsums[w_];
        if (w_ < wv) woff += s;
        total += s;
    }
    if (i < N) rowptr[i] = v + woff - orig;
    if (t == 0) bsum[blockIdx.x] = total;
}

__global__ void scan_bsums(const int* __restrict__ bsum, int* __restrict__ bsum2,
                           int* __restrict__ rowptr, int nb, int N) {
    int lane = threadIdx.x;   // 64 threads, nb <= 64
    int v = (lane < nb) ? bsum[lane] : 0;
    int orig = v;
    #pragma unroll
    for (int off = 1; off < 64; off <<= 1) {
        int n = __shfl_up(v, off, 64);
        if (lane >= off) v += n;
    }
    if (lane < nb) bsum2[lane] = v - orig;
    if (lane == 63) rowptr[N] = v;
}

__global__ __launch_bounds__(1024) void scan_add(
        int* __restrict__ rowptr, const int* __restrict__ bsum2, int N) {
    int i = blockIdx.x * 1024 + threadIdx.x;
    if (i < N) rowptr[i] += bsum2[blockIdx.x];
}

// ---------------------------------------------------------------------------
// Scatter: store PRE-SCALED byte offsets (s * 512 = s<<9) so gat_node's
// gather address is a single v_or with the lane's channel-byte offset.
__global__ void scatter_edges(const int* __restrict__ eidx, int E, int N,
                              const int* __restrict__ rowptr,
                              int* __restrict__ fill, int* __restrict__ srcS) {
    int w = blockIdx.x * blockDim.x + threadIdx.x;
    int Etot = E + N;
    if (w >= Etot) return;
    int s, d;
    if (w < E) { s = eidx[w]; d = eidx[E + w]; }
    else       { s = w - E;   d = w - E; }
    int pos = rowptr[d] + atomicAdd(&fill[d], 1);
    srcS[pos] = s << 9;          // byte offset of row s (HC * 2B = 512)
}

// ---------------------------------------------------------------------------
// Fused GATv2 per-node: one wave per dst node, ONE-SHOT blocks (4 nodes per
// 256-block). Measured-best structure (R1/R5) — FROZEN. R2/R3/R4
// restructures (rotation pipeline, hoisted gathers, persistent grid) all
// regressed: occupancy/load-balance beat hand scheduling here.
// Two edges per wave per step (half-waves h=0/1), 8 channels per lane.
// LAYER1: ELU + bf16 SWIZZLED store (feeds layer-2 GEMM DMA); else fp32.
template <int LAYER1>
__global__ __launch_bounds__(256) void gat_node(
        const ushort* __restrict__ xl, const ushort* __restrict__ xr,
        const float* __restrict__ att, const float* __restrict__ bias,
        const int* __restrict__ rowptr, const unsigned* __restrict__ srcB,
        void* __restrict__ outp, int N) {
    int node = blockIdx.x * 4 + (threadIdx.x >> 6);
    int lane = threadIdx.x & 63;
    if (node >= N) return;
    int h = lane >> 5;                       // which edge of the pair
    int q = lane & 31;                       // 16B-block index within row
    unsigned cb = (unsigned)q * 16u;         // byte offset within row
    const char* xbase = (const char*)xl;
    int beg = rowptr[node], end = rowptr[node + 1];

    long long nbase = (long long)node * HC;
    uint4 xu = *(const uint4*)(xr + nbase + q * 8);
    float xr0 = __uint_as_float(xu.x << 16);
    float xr1 = __uint_as_float(xu.x & 0xffff0000u);
    float xr2 = __uint_as_float(xu.y << 16);
    float xr3 = __uint_as_float(xu.y & 0xffff0000u);
    float xr4 = __uint_as_float(xu.z << 16);
    float xr5 = __uint_as_float(xu.z & 0xffff0000u);
    float xr6 = __uint_as_float(xu.w << 16);
    float xr7 = __uint_as_float(xu.w & 0xffff0000u);
    float4 av0 = *(const float4*)(att + q * 8);
    float4 av1 = *(const float4*)(att + q * 8 + 4);

    float ssA = 0.f, ssB = 0.f;
    float aA0 = 0.f, aA1 = 0.f, aA2 = 0.f, aA3 = 0.f;
    float aA4 = 0.f, aA5 = 0.f, aA6 = 0.f, aA7 = 0.f;
    float aB0 = 0.f, aB1 = 0.f, aB2 = 0.f, aB3 = 0.f;
    float aB4 = 0.f, aB5 = 0.f, aB6 = 0.f, aB7 = 0.f;

// EDGE2 processes edges (P, P+h): 2 edges per wave. ALLV=0 -> single valid
// edge at P; half-1 lanes clamp to P and contribute ex=0.
#define EDGE2(P, SFX, ALLV)                                                    \
    {                                                                          \
        int pe = (P) + ((ALLV) ? h : 0);                                       \
        unsigned off = srcB[pe] | cb;                                          \
        uint4 dv = *(const uint4*)(xbase + off);                               \
        float v0 = __uint_as_float(dv.x << 16);                                \
        float v1 = __uint_as_float(dv.x & 0xffff0000u);                        \
        float v2 = __uint_as_float(dv.y << 16);                                \
        float v3 = __uint_as_float(dv.y & 0xffff0000u);                        \
        float v4 = __uint_as_float(dv.z << 16);                                \
        float v5 = __uint_as_float(dv.z & 0xffff0000u);                        \
        float v6 = __uint_as_float(dv.w << 16);                                \
        float v7 = __uint_as_float(dv.w & 0xffff0000u);                        \
        float t0 = v0 + xr0, t1 = v1 + xr1, t2 = v2 + xr2, t3 = v3 + xr3;      \
        float t4 = v4 + xr4, t5 = v5 + xr5, t6 = v6 + xr6, t7 = v7 + xr7;      \
        float st = av0.x * t0;                                                 \
        st = fmaf(av0.y, t1, st); st = fmaf(av0.z, t2, st);                    \
        st = fmaf(av0.w, t3, st); st = fmaf(av1.x, t4, st);                    \
        st = fmaf(av1.y, t5, st); st = fmaf(av1.z, t6, st);                    \
        st = fmaf(av1.w, t7, st);                                              \
        float sa = av0.x * fabsf(t0);                                          \
        sa = fmaf(av0.y, fabsf(t1), sa); sa = fmaf(av0.z, fabsf(t2), sa);      \
        sa = fmaf(av0.w, fabsf(t3), sa); sa = fmaf(av1.x, fabsf(t4), sa);      \
        sa = fmaf(av1.y, fabsf(t5), sa); sa = fmaf(av1.z, fabsf(t6), sa);      \
        sa = fmaf(av1.w, fabsf(t7), sa);                                       \
        float sc = fmaf(0.6f, st, 0.4f * sa);                                  \
        sc += __shfl_xor(sc, 1, 64);                                           \
        sc += __shfl_xor(sc, 2, 64);                                           \
        float ex = ((ALLV) || h == 0) ? __expf(sc) : 0.f;                      \
        ss##SFX += ex;                                                         \
        a##SFX##0 = fmaf(ex, v0, a##SFX##0);                                   \
        a##SFX##1 = fmaf(ex, v1, a##SFX##1);                                   \
        a##SFX##2 = fmaf(ex, v2, a##SFX##2);                                   \
        a##SFX##3 = fmaf(ex, v3, a##SFX##3);                                   \
        a##SFX##4 = fmaf(ex, v4, a##SFX##4);                                   \
        a##SFX##5 = fmaf(ex, v5, a##SFX##5);                                   \
        a##SFX##6 = fmaf(ex, v6, a##SFX##6);                                   \
        a##SFX##7 = fmaf(ex, v7, a##SFX##7);                                   \
    }

    int p = beg;
    for (; p + 4 <= end; p += 4) {           // unroll-2: 4 edges in flight
        EDGE2(p, A, 1)
        EDGE2(p + 2, B, 1)
    }
    if (p + 2 <= end) { EDGE2(p, A, 1) p += 2; }
    if (p < end) { EDGE2(p, B, 0) }
#undef EDGE2

    // merge the two half-wave partial sums (once per node)
    float ss = ssA + ssB;
    ss += __shfl_xor(ss, 32, 64);
    float a0 = aA0 + aB0; a0 += __shfl_xor(a0, 32, 64);
    float a1 = aA1 + aB1; a1 += __shfl_xor(a1, 32, 64);
    float a2 = aA2 + aB2; a2 += __shfl_xor(a2, 32, 64);
    float a3 = aA3 + aB3; a3 += __shfl_xor(a3, 32, 64);
    float a4 = aA4 + aB4; a4 += __shfl_xor(a4, 32, 64);
    float a5 = aA5 + aB5; a5 += __shfl_xor(a5, 32, 64);
    float a6 = aA6 + aB6; a6 += __shfl_xor(a6, 32, 64);
    float a7 = aA7 + aB7; a7 += __shfl_xor(a7, 32, 64);

    float inv = 1.f / ss;
    float4 bv0 = *(const float4*)(bias + q * 8);
    float4 bv1 = *(const float4*)(bias + q * 8 + 4);
    float o0 = fmaf(a0, inv, bv0.x);
    float o1 = fmaf(a1, inv, bv0.y);
    float o2 = fmaf(a2, inv, bv0.z);
    float o3 = fmaf(a3, inv, bv0.w);
    float o4 = fmaf(a4, inv, bv1.x);
    float o5 = fmaf(a5, inv, bv1.y);
    float o6 = fmaf(a6, inv, bv1.z);
    float o7 = fmaf(a7, inv, bv1.w);

    if (LAYER1) {
        // each half stores its 4 channels of the 16B block q
        float s0 = h ? o4 : o0;
        float s1 = h ? o5 : o1;
        float s2 = h ? o6 : o2;
        float s3 = h ? o7 : o3;
        s0 = s0 > 0.f ? s0 : expm1f(s0);
        s1 = s1 > 0.f ? s1 : expm1f(s1);
        s2 = s2 > 0.f ? s2 : expm1f(s2);
        s3 = s3 > 0.f ? s3 : expm1f(s3);
        ushort4 pk;
        pk.x = bf16_rne(s0); pk.y = bf16_rne(s1);
        pk.z = bf16_rne(s2); pk.w = bf16_rne(s3);
        int jx = q ^ (node & 7);             // swizzled 16B-block position
        *(ushort4*)((ushort*)outp + nbase + jx * 8 + h * 4) = pk;
    } else {
        float4 ov = h ? make_float4(o4, o5, o6, o7)
                      : make_float4(o0, o1, o2, o3);
        *(float4*)((float*)outp + nbase + q * 8 + h * 4) = ov;
    }
}

// ---------------------------------------------------------------------------
extern "C" void kernel_launch(void* const* d_in, const int* in_sizes, int n_in,
                              void* d_out, int out_size, void* d_ws, size_t ws_size,
                              hipStream_t stream) {
    const float* x    = (const float*)d_in[0];
    const int*   eidx = (const int*)d_in[1];
    const float* Wl1  = (const float*)d_in[2];
    const float* Wr1  = (const float*)d_in[3];
    const float* att1 = (const float*)d_in[4];
    const float* b1   = (const float*)d_in[5];
    const float* Wl2  = (const float*)d_in[6];
    const float* Wr2  = (const float*)d_in[7];
    const float* att2 = (const float*)d_in[8];
    const float* b2   = (const float*)d_in[9];
    float* out = (float*)d_out;

    const int N = in_sizes[0] / HC;       // 50000
    const int E = in_sizes[1] / 2;        // 800000
    const int Etot = E + N;
    const long long NHC = (long long)N * HC;

    // workspace layout (16B-aligned bf16 region first)
    ushort* xl   = (ushort*)d_ws;         // N*HC bf16 (plain)
    ushort* xr   = xl + NHC;              // N*HC     (plain)
    ushort* hbuf = xr + NHC;              // N*HC     (swizzled)
    ushort* xb   = hbuf + NHC;            // N*HC     (swizzled)
    ushort* wt1  = xb + NHC;              // 512*HC   (swizzled)
    ushort* wt2  = wt1 + 512 * HC;        // 512*HC   (swizzled)
    int* rowptr  = (int*)(wt2 + 512 * HC);// N+1
    int* counts  = rowptr + (N + 1);      // N
    int* fill    = counts + N;            // N (contiguous with counts)
    int* bsum    = fill + N;              // 64
    int* bsum2   = bsum + 64;             // 64
    int* srcS    = bsum2 + 64;            // Etot

    const int TB = 256;
    dim3 blk(TB);
    int gEdgesT = (Etot + TB - 1) / TB;
    int mtTiles = (N + 127) / 128;                // 391
    int gGemm   = ((mtTiles + 7) / 8) * 32;       // supergrouped (8 mt x 4 nt)
    int gNode   = (N + 3) / 4;
    int nb      = (N + 1023) / 1024;      // 49 <= 64
    long long nblk = NHC / 8;
    int gCvt    = (int)((nblk + TB - 1) / TB);

    // ---- one-time conversions + CSR build (R5-proven sequence) ----
    cvt_bf16_sw<<<gCvt, blk, 0, stream>>>(x, xb, nblk);
    build_wt<<<512, blk, 0, stream>>>(Wl1, Wr1, wt1);
    build_wt<<<512, blk, 0, stream>>>(Wl2, Wr2, wt2);
    hipMemsetAsync(counts, 0, (size_t)2 * N * sizeof(int), stream);
    hist_dst<<<gEdgesT, blk, 0, stream>>>(eidx, E, N, counts);
    scan_local<<<nb, 1024, 0, stream>>>(counts, rowptr, bsum, N);
    scan_bsums<<<1, 64, 0, stream>>>(bsum, bsum2, rowptr, nb, N);
    scan_add<<<nb, 1024, 0, stream>>>(rowptr, bsum2, N);
    scatter_edges<<<gEdgesT, blk, 0, stream>>>(eidx, E, N, rowptr, fill, srcS);

    // ================= layer 1 =================
    gemm_mfma<<<gGemm, blk, 0, stream>>>(xb, wt1, xl, xr, N);
    gat_node<1><<<gNode, blk, 0, stream>>>(xl, xr, att1, b1, rowptr,
                                           (const unsigned*)srcS, hbuf, N);

    // ================= layer 2 =================
    gemm_mfma<<<gGemm, blk, 0, stream>>>(hbuf, wt2, xl, xr, N);
    gat_node<0><<<gNode, blk, 0, stream>>>(xl, xr, att2, b2, rowptr,
                                           (const unsigned*)srcS, out, N);
}